// Round 5
// baseline (2472.026 us; speedup 1.0000x reference)
//
#include <hip/hip_runtime.h>
#include <hip/hip_bf16.h>
#include <stdint.h>

typedef _Float16 f16x8 __attribute__((ext_vector_type(8)));
typedef _Float16 f16x4 __attribute__((ext_vector_type(4)));
typedef float    f32x4 __attribute__((ext_vector_type(4)));

// ---------------------------------------------------------------------------
// global->LDS direct load, 16B per lane; LDS dest = wave-uniform base + lane*16
// ---------------------------------------------------------------------------
__device__ __forceinline__ void gload_lds16(const void* g, void* l) {
  __builtin_amdgcn_global_load_lds(
      reinterpret_cast<const __attribute__((address_space(1))) void*>(
          reinterpret_cast<uintptr_t>(g)),
      reinterpret_cast<__attribute__((address_space(3))) void*>(
          reinterpret_cast<uintptr_t>(l)),
      16, 0, 0);
}

// XOR swizzle within each 128B row, keyed off row&7 (bits 7-9 of byte offset).
__device__ __forceinline__ int swz(int o) { return o ^ ((o >> 3) & 0x70); }

// ---------------------------------------------------------------------------
// prepass 1: edge_rep = f16(relu(edge_ctx @ W_post_emb + b))  (1280x512x1024)
// ---------------------------------------------------------------------------
__global__ void k_edge(const float* __restrict__ ec, const float* __restrict__ W,
                       const float* __restrict__ b, _Float16* __restrict__ er)
{
  __shared__ float sec[8 * 512];
  const int t  = threadIdx.x;
  const int rb = blockIdx.x * 8;
#pragma unroll
  for (int j = 0; j < 16; ++j)
    sec[j * 256 + t] = ec[(size_t)rb * 512 + j * 256 + t];
  __syncthreads();

  const int c4 = t * 4;
  f32x4 acc[8];
#pragma unroll
  for (int r = 0; r < 8; ++r) acc[r] = f32x4{0.f, 0.f, 0.f, 0.f};

  for (int k = 0; k < 512; ++k) {
    f32x4 w = *reinterpret_cast<const f32x4*>(W + (size_t)k * 1024 + c4);
#pragma unroll
    for (int r = 0; r < 8; ++r) acc[r] += sec[r * 512 + k] * w;
  }
  f32x4 bb = *reinterpret_cast<const f32x4*>(b + c4);
#pragma unroll
  for (int r = 0; r < 8; ++r) {
    f32x4 o = acc[r] + bb;
    f16x4 h;
#pragma unroll
    for (int i = 0; i < 4; ++i) h[i] = (_Float16)(o[i] > 0.f ? o[i] : 0.f);
    *reinterpret_cast<f16x4*>(er + (size_t)(rb + r) * 1024 + c4) = h;
  }
}

// ---------------------------------------------------------------------------
// prepass 2: gather -> A_cat[r][c] = edge_rep[(c<512?p0:p1)][c]   (f16)
// ---------------------------------------------------------------------------
__global__ void k_gather(const _Float16* __restrict__ er, const int* __restrict__ pidx,
                         _Float16* __restrict__ Acat)
{
  const int r  = blockIdx.x;
  const int c4 = threadIdx.x * 4;
  const int obj = pidx[2 * r + (c4 >= 512 ? 1 : 0)];
  f16x4 v = *reinterpret_cast<const f16x4*>(er + (size_t)obj * 1024 + c4);
  *reinterpret_cast<f16x4*>(Acat + (size_t)r * 1024 + c4) = v;
}

// ---------------------------------------------------------------------------
// prepass 3: fp32 -> fp16 convert (union_features), 8 elems/thread
// ---------------------------------------------------------------------------
__global__ void k_cvt(const float* __restrict__ in, _Float16* __restrict__ out)
{
  const size_t g = (size_t)blockIdx.x * 256 + threadIdx.x;
  const f32x4* p = reinterpret_cast<const f32x4*>(in) + g * 2;
  f32x4 v0 = p[0], v1 = p[1];
  f16x8 h;
  h[0] = (_Float16)v0[0]; h[1] = (_Float16)v0[1];
  h[2] = (_Float16)v0[2]; h[3] = (_Float16)v0[3];
  h[4] = (_Float16)v1[0]; h[5] = (_Float16)v1[1];
  h[6] = (_Float16)v1[2]; h[7] = (_Float16)v1[3];
  *(reinterpret_cast<f16x8*>(out) + g) = h;
}

// ---------------------------------------------------------------------------
// prepass 4: Wt[n][k] = f16(W[k][n])  (tiled transpose via LDS)
// ---------------------------------------------------------------------------
__global__ void k_wt(const float* __restrict__ W, _Float16* __restrict__ Wt,
                     int K, int N)
{
  __shared__ float tile[64][65];
  const int ntn = N >> 6;
  const int kt = blockIdx.x / ntn, nt = blockIdx.x % ntn;
  const int tx = threadIdx.x & 63, ty = threadIdx.x >> 6;
  const int k0 = kt * 64, n0 = nt * 64;
#pragma unroll
  for (int j = 0; j < 16; ++j) {
    int kr = j * 4 + ty;
    tile[kr][tx] = W[(size_t)(k0 + kr) * N + n0 + tx];
  }
  __syncthreads();
#pragma unroll
  for (int j = 0; j < 16; ++j) {
    int nr = j * 4 + ty;
    Wt[(size_t)(n0 + nr) * K + k0 + tx] = (_Float16)tile[tx][nr];
  }
}

// ---------------------------------------------------------------------------
// staging: NI chunks of 8KB; linear LDS dest, source pre-swizzled.
// ---------------------------------------------------------------------------
template<int NI>
__device__ __forceinline__ void stage_tile(const _Float16* __restrict__ src, int ldk,
                                           int rcBase, int kt, _Float16* sbuf, int tid)
{
#pragma unroll
  for (int j = 0; j < NI; ++j) {
    int o  = j * 8192 + tid * 16;          // linear LDS byte offset
    int op = swz(o);                        // logical (row,kbyte) it must hold
    int r  = op >> 7;
    int kh = (op & 127) >> 1;
    gload_lds16(src + (size_t)(rcBase + r) * ldk + kt + kh,
                sbuf + (o - (tid & 63) * 16) / 2);   // wave-uniform base
  }
}

// ---------------------------------------------------------------------------
// single-acc GEMM: C = A(MxK) @ Bt(NxK)^T + bias, 256x256 tile, BK=64,
// 512 thr = 8 waves (2x4), wave tile 128x64. 2 LDS buffers (128KB),
// 4-phase interleave, 1 barrier/tile, vmcnt(0) at boundary.
// EPI=0: store f16 P.  EPI=1: out = (acc+bias) * P  (f32).
// ---------------------------------------------------------------------------
template<int KDIM, int EPI>
__global__ __launch_bounds__(512, 2) void k_gemm(
    const _Float16* __restrict__ A, const _Float16* __restrict__ Bt,
    const float* __restrict__ bias, const _Float16* __restrict__ P,
    float* __restrict__ out, _Float16* __restrict__ Pout)
{
  constexpr int NT = KDIM / 64;
  extern __shared__ char smem[];                     // 128 KiB

  const int tid  = threadIdx.x;
  const int lane = tid & 63, lr = lane & 15, lg = lane >> 4;
  const int wid  = tid >> 6, wr = wid >> 2, wc = wid & 3;     // 2x4 wave grid

  // XCD-aware bijective swizzle over 4096 blocks (512/XCD), col-tile fastest
  const int bid = blockIdx.x;
  const int swb = (bid & 7) * 512 + (bid >> 3);
  const int rowBase = (swb >> 4) * 256;
  const int colBase = (swb & 15) * 256;

  const int key = (lr & 7) << 4;
  int kb[2];
  kb[0] = (lg * 16) ^ key;
  kb[1] = (64 + lg * 16) ^ key;

  f16x8 af[4][2], bf[2][2], bg[2][2];
  f32x4 acc[8][4] = {};

  // prologue: stage tile 0
  stage_tile<4>(A,  KDIM, rowBase, 0, reinterpret_cast<_Float16*>(smem), tid);
  stage_tile<4>(Bt, KDIM, colBase, 0, reinterpret_cast<_Float16*>(smem + 65536), tid);
  asm volatile("s_waitcnt vmcnt(0)" ::: "memory");
  __builtin_amdgcn_s_barrier();

  for (int t = 0; t < NT; ++t) {
    const int cur = t & 1;
    char* sAc = smem + cur * 32768;
    char* sBc = smem + 65536 + cur * 32768;
    _Float16* An = reinterpret_cast<_Float16*>(smem + (cur ^ 1) * 32768);
    _Float16* Bn = reinterpret_cast<_Float16*>(smem + 65536 + (cur ^ 1) * 32768);
    const char* aB = sAc + (wr * 128 + lr) * 128;
    const char* bB = sBc + (wc * 64 + lr) * 128;

    // ---- phase 0: read af[mh=0] + bf[nh=0]; stage next A ----
    if (t + 1 < NT) stage_tile<4>(A, KDIM, rowBase, (t + 1) * 64, An, tid);
#pragma unroll
    for (int m = 0; m < 4; ++m)
#pragma unroll
      for (int ks = 0; ks < 2; ++ks)
        af[m][ks] = *reinterpret_cast<const f16x8*>(aB + m * 2048 + kb[ks]);
#pragma unroll
    for (int n = 0; n < 2; ++n)
#pragma unroll
      for (int ks = 0; ks < 2; ++ks)
        bf[n][ks] = *reinterpret_cast<const f16x8*>(bB + n * 2048 + kb[ks]);
    asm volatile("s_waitcnt lgkmcnt(0)" ::: "memory");
    __builtin_amdgcn_sched_barrier(0);
    __builtin_amdgcn_s_setprio(1);
#pragma unroll
    for (int m = 0; m < 4; ++m)
#pragma unroll
      for (int n = 0; n < 2; ++n)
#pragma unroll
        for (int ks = 0; ks < 2; ++ks)
          acc[m][n] = __builtin_amdgcn_mfma_f32_16x16x32_f16(af[m][ks], bf[n][ks], acc[m][n], 0, 0, 0);
    __builtin_amdgcn_s_setprio(0);

    // ---- phase 1: read bg[nh=1]; stage next B ----
    if (t + 1 < NT) stage_tile<4>(Bt, KDIM, colBase, (t + 1) * 64, Bn, tid);
#pragma unroll
    for (int n = 0; n < 2; ++n)
#pragma unroll
      for (int ks = 0; ks < 2; ++ks)
        bg[n][ks] = *reinterpret_cast<const f16x8*>(bB + (2 + n) * 2048 + kb[ks]);
    asm volatile("s_waitcnt lgkmcnt(0)" ::: "memory");
    __builtin_amdgcn_sched_barrier(0);
    __builtin_amdgcn_s_setprio(1);
#pragma unroll
    for (int m = 0; m < 4; ++m)
#pragma unroll
      for (int n = 0; n < 2; ++n)
#pragma unroll
        for (int ks = 0; ks < 2; ++ks)
          acc[m][2 + n] = __builtin_amdgcn_mfma_f32_16x16x32_f16(af[m][ks], bg[n][ks], acc[m][2 + n], 0, 0, 0);
    __builtin_amdgcn_s_setprio(0);

    // ---- phase 2: read af[mh=1] (overwrite) ----
#pragma unroll
    for (int m = 0; m < 4; ++m)
#pragma unroll
      for (int ks = 0; ks < 2; ++ks)
        af[m][ks] = *reinterpret_cast<const f16x8*>(aB + (4 + m) * 2048 + kb[ks]);
    asm volatile("s_waitcnt lgkmcnt(0)" ::: "memory");
    __builtin_amdgcn_sched_barrier(0);
    __builtin_amdgcn_s_setprio(1);
#pragma unroll
    for (int m = 0; m < 4; ++m)
#pragma unroll
      for (int n = 0; n < 2; ++n)
#pragma unroll
        for (int ks = 0; ks < 2; ++ks)
          acc[4 + m][n] = __builtin_amdgcn_mfma_f32_16x16x32_f16(af[m][ks], bf[n][ks], acc[4 + m][n], 0, 0, 0);
    __builtin_amdgcn_s_setprio(0);

    // ---- phase 3: MFMA only ----
    __builtin_amdgcn_s_setprio(1);
#pragma unroll
    for (int m = 0; m < 4; ++m)
#pragma unroll
      for (int n = 0; n < 2; ++n)
#pragma unroll
        for (int ks = 0; ks < 2; ++ks)
          acc[4 + m][2 + n] = __builtin_amdgcn_mfma_f32_16x16x32_f16(af[m][ks], bg[n][ks], acc[4 + m][2 + n], 0, 0, 0);
    __builtin_amdgcn_s_setprio(0);

    // ---- tile boundary: next tile's 8 loads done (issued >=2 phases ago) ----
    asm volatile("s_waitcnt vmcnt(0)" ::: "memory");
    __builtin_amdgcn_s_barrier();
    __builtin_amdgcn_sched_barrier(0);
  }

  // ---------------- epilogue ----------------
#pragma unroll
  for (int n = 0; n < 4; ++n) {
    const int col = colBase + wc * 64 + n * 16 + lr;
    const float bs = bias[col];
#pragma unroll
    for (int m = 0; m < 8; ++m) {
      const size_t row0 = rowBase + wr * 128 + m * 16 + lg * 4;
#pragma unroll
      for (int i = 0; i < 4; ++i) {
        const size_t idx = (row0 + i) * 4096 + col;
        if (EPI == 0) Pout[idx] = (_Float16)(acc[m][n][i] + bs);
        else          out[idx]  = (acc[m][n][i] + bs) * (float)P[idx];
      }
    }
  }
}

// ---------------------------------------------------------------------------
extern "C" void kernel_launch(void* const* d_in, const int* in_sizes, int n_in,
                              void* d_out, int out_size, void* d_ws, size_t ws_size,
                              hipStream_t stream)
{
  const float* edge_ctx = (const float*)d_in[0];
  const int*   pair_idx = (const int*)d_in[1];
  const float* uf       = (const float*)d_in[2];
  const float* Wpe      = (const float*)d_in[3];
  const float* bpe      = (const float*)d_in[4];
  const float* Wpc      = (const float*)d_in[5];
  const float* bpc      = (const float*)d_in[6];
  const float* Wup      = (const float*)d_in[7];
  const float* bup      = (const float*)d_in[8];
  float* out = (float*)d_out;

  char* ws = (char*)d_ws;
  size_t off = 0;
  _Float16* Pbuf = (_Float16*)(ws + off); off += 536870912;   // 512 MB
  _Float16* Acat = (_Float16*)(ws + off); off += 134217728;   // 128 MB
  _Float16* Auf  = (_Float16*)(ws + off); off += 268435456;   // 256 MB
  _Float16* Btc  = (_Float16*)(ws + off); off += 8388608;     //   8 MB
  _Float16* Btu  = (_Float16*)(ws + off); off += 16777216;    //  16 MB
  _Float16* edge_rep = (_Float16*)(ws + off);                 // 2.6 MB

  (void)hipFuncSetAttribute((const void*)(k_gemm<1024, 0>),
                            hipFuncAttributeMaxDynamicSharedMemorySize, 131072);
  (void)hipFuncSetAttribute((const void*)(k_gemm<2048, 1>),
                            hipFuncAttributeMaxDynamicSharedMemorySize, 131072);

  k_edge<<<160, 256, 0, stream>>>(edge_ctx, Wpe, bpe, edge_rep);
  k_wt<<<(1024 / 64) * (4096 / 64), 256, 0, stream>>>(Wpc, Btc, 1024, 4096);
  k_wt<<<(2048 / 64) * (4096 / 64), 256, 0, stream>>>(Wup, Btu, 2048, 4096);
  k_gather<<<65536, 256, 0, stream>>>(edge_rep, pair_idx, Acat);
  k_cvt<<<65536, 256, 0, stream>>>(uf, Auf);

  k_gemm<1024, 0><<<4096, 512, 131072, stream>>>(Acat, Btc, bpc, nullptr, nullptr, Pbuf);
  k_gemm<2048, 1><<<4096, 512, 131072, stream>>>(Auf, Btu, bup, Pbuf, out, nullptr);
}

// Round 6
// 2449.845 us; speedup vs baseline: 1.0091x; 1.0091x over previous
//
#include <hip/hip_runtime.h>
#include <hip/hip_bf16.h>
#include <stdint.h>

typedef _Float16 f16x8 __attribute__((ext_vector_type(8)));
typedef _Float16 f16x4 __attribute__((ext_vector_type(4)));
typedef float    f32x4 __attribute__((ext_vector_type(4)));

// ---------------------------------------------------------------------------
// global->LDS direct load, 16B per lane; LDS dest = wave-uniform base + lane*16
// ---------------------------------------------------------------------------
__device__ __forceinline__ void gload_lds16(const void* g, void* l) {
  __builtin_amdgcn_global_load_lds(
      reinterpret_cast<const __attribute__((address_space(1))) void*>(
          reinterpret_cast<uintptr_t>(g)),
      reinterpret_cast<__attribute__((address_space(3))) void*>(
          reinterpret_cast<uintptr_t>(l)),
      16, 0, 0);
}

// XOR swizzle within each 128B row, keyed off row&7 (bits 7-9 of byte offset).
__device__ __forceinline__ int swz(int o) { return o ^ ((o >> 3) & 0x70); }

// ---------------------------------------------------------------------------
// prepass 1: edge_rep = f16(relu(edge_ctx @ W_post_emb + b))  (1280x512x1024)
// ---------------------------------------------------------------------------
__global__ void k_edge(const float* __restrict__ ec, const float* __restrict__ W,
                       const float* __restrict__ b, _Float16* __restrict__ er)
{
  __shared__ float sec[8 * 512];
  const int t  = threadIdx.x;
  const int rb = blockIdx.x * 8;
#pragma unroll
  for (int j = 0; j < 16; ++j)
    sec[j * 256 + t] = ec[(size_t)rb * 512 + j * 256 + t];
  __syncthreads();

  const int c4 = t * 4;
  f32x4 acc[8];
#pragma unroll
  for (int r = 0; r < 8; ++r) acc[r] = f32x4{0.f, 0.f, 0.f, 0.f};

  for (int k = 0; k < 512; ++k) {
    f32x4 w = *reinterpret_cast<const f32x4*>(W + (size_t)k * 1024 + c4);
#pragma unroll
    for (int r = 0; r < 8; ++r) acc[r] += sec[r * 512 + k] * w;
  }
  f32x4 bb = *reinterpret_cast<const f32x4*>(b + c4);
#pragma unroll
  for (int r = 0; r < 8; ++r) {
    f32x4 o = acc[r] + bb;
    f16x4 h;
#pragma unroll
    for (int i = 0; i < 4; ++i) h[i] = (_Float16)(o[i] > 0.f ? o[i] : 0.f);
    *reinterpret_cast<f16x4*>(er + (size_t)(rb + r) * 1024 + c4) = h;
  }
}

// ---------------------------------------------------------------------------
// prepass 2: gather -> A_cat[r][c] = edge_rep[(c<512?p0:p1)][c]   (f16)
// ---------------------------------------------------------------------------
__global__ void k_gather(const _Float16* __restrict__ er, const int* __restrict__ pidx,
                         _Float16* __restrict__ Acat)
{
  const int r  = blockIdx.x;
  const int c4 = threadIdx.x * 4;
  const int obj = pidx[2 * r + (c4 >= 512 ? 1 : 0)];
  f16x4 v = *reinterpret_cast<const f16x4*>(er + (size_t)obj * 1024 + c4);
  *reinterpret_cast<f16x4*>(Acat + (size_t)r * 1024 + c4) = v;
}

// ---------------------------------------------------------------------------
// prepass 3: fp32 -> fp16 convert (union_features), 8 elems/thread
// ---------------------------------------------------------------------------
__global__ void k_cvt(const float* __restrict__ in, _Float16* __restrict__ out)
{
  const size_t g = (size_t)blockIdx.x * 256 + threadIdx.x;
  const f32x4* p = reinterpret_cast<const f32x4*>(in) + g * 2;
  f32x4 v0 = p[0], v1 = p[1];
  f16x8 h;
  h[0] = (_Float16)v0[0]; h[1] = (_Float16)v0[1];
  h[2] = (_Float16)v0[2]; h[3] = (_Float16)v0[3];
  h[4] = (_Float16)v1[0]; h[5] = (_Float16)v1[1];
  h[6] = (_Float16)v1[2]; h[7] = (_Float16)v1[3];
  *(reinterpret_cast<f16x8*>(out) + g) = h;
}

// ---------------------------------------------------------------------------
// prepass 4: Wt[n][k] = f16(W[k][n])  (tiled transpose via LDS)
// ---------------------------------------------------------------------------
__global__ void k_wt(const float* __restrict__ W, _Float16* __restrict__ Wt,
                     int K, int N)
{
  __shared__ float tile[64][65];
  const int ntn = N >> 6;
  const int kt = blockIdx.x / ntn, nt = blockIdx.x % ntn;
  const int tx = threadIdx.x & 63, ty = threadIdx.x >> 6;
  const int k0 = kt * 64, n0 = nt * 64;
#pragma unroll
  for (int j = 0; j < 16; ++j) {
    int kr = j * 4 + ty;
    tile[kr][tx] = W[(size_t)(k0 + kr) * N + n0 + tx];
  }
  __syncthreads();
#pragma unroll
  for (int j = 0; j < 16; ++j) {
    int nr = j * 4 + ty;
    Wt[(size_t)(n0 + nr) * K + k0 + tx] = (_Float16)tile[tx][nr];
  }
}

// ---------------------------------------------------------------------------
// half-tile staging (16KB, 2 loads/thread). A-sub[mh]: region row idx =
// wr*64+rr -> global row rowBase + wr*128 + mh*64 + rr.
// B-sub[nh]: region row idx = wc*32+rr -> global row colBase + wc*64 + nh*32+rr.
// ---------------------------------------------------------------------------
__device__ __forceinline__ void stage_half_A(const _Float16* __restrict__ A, int ldk,
                                             int rowBase, int mh, int kt,
                                             char* region, int tid)
{
#pragma unroll
  for (int j = 0; j < 2; ++j) {
    int o   = j * 8192 + tid * 16;
    int op  = swz(o);
    int idx = op >> 7;                       // 0..127
    int row = rowBase + (idx >> 6) * 128 + mh * 64 + (idx & 63);
    int kh  = (op & 127) >> 1;
    gload_lds16(A + (size_t)row * ldk + kt + kh, region + (o - (tid & 63) * 16));
  }
}

__device__ __forceinline__ void stage_half_B(const _Float16* __restrict__ Bt, int ldk,
                                             int colBase, int nh, int kt,
                                             char* region, int tid)
{
#pragma unroll
  for (int j = 0; j < 2; ++j) {
    int o   = j * 8192 + tid * 16;
    int op  = swz(o);
    int idx = op >> 7;                       // 0..127
    int row = colBase + (idx >> 5) * 64 + nh * 32 + (idx & 31);
    int kh  = (op & 127) >> 1;
    gload_lds16(Bt + (size_t)row * ldk + kt + kh, region + (o - (tid & 63) * 16));
  }
}

// ---------------------------------------------------------------------------
// single-acc GEMM: C = A(MxK) @ Bt(NxK)^T + bias, 256x256 tile, BK=64,
// 512 thr = 8 waves (2x4), wave tile 128x64.
// m201-style 8-phase/2-K-tile schedule: 4 phases/tile, 1 half-tile staged per
// phase, counted vmcnt(6) once per tile (3 half-tiles stay in flight),
// 2 barriers/phase. LDS: A 4x16KB + B 4x16KB = 128KB.
// EPI=0: store f16 P.  EPI=1: out = (acc+bias) * P  (f32).
// ---------------------------------------------------------------------------
template<int KDIM, int EPI>
__global__ __launch_bounds__(512, 2) void k_gemm(
    const _Float16* __restrict__ A, const _Float16* __restrict__ Bt,
    const float* __restrict__ bias, const _Float16* __restrict__ P,
    float* __restrict__ out, _Float16* __restrict__ Pout)
{
  constexpr int NT = KDIM / 64;
  extern __shared__ char smem[];                     // 128 KiB
  // A: smem + dbuf*32768 + mh*16384 ; B: smem + 65536 + dbuf*32768 + nh*16384

  const int tid  = threadIdx.x;
  const int lane = tid & 63, lr = lane & 15, lg = lane >> 4;
  const int wid  = tid >> 6, wr = wid >> 2, wc = wid & 3;     // 2x4 wave grid

  // XCD-aware bijective swizzle over 4096 blocks (512/XCD), col-tile fastest
  const int bid = blockIdx.x;
  const int swb = (bid & 7) * 512 + (bid >> 3);
  const int rowBase = (swb >> 4) * 256;
  const int colBase = (swb & 15) * 256;

  const int key = (lr & 7) << 4;
  int kb[2];
  kb[0] = (lg * 16) ^ key;
  kb[1] = (64 + lg * 16) ^ key;
  const int aoff = (wr * 64 + lr) * 128;   // row offset within A region
  const int boff = (wc * 32 + lr) * 128;   // row offset within B region

  f16x8 af[4][2], bf0[2][2], bf1[2][2];
  f32x4 acc[8][4] = {};

  // ---- prologue: 7 half-tiles in FIFO order, then vmcnt(4) ----
  stage_half_A(A,  KDIM, rowBase, 0, 0, smem, tid);                    // A0(0)
  stage_half_B(Bt, KDIM, colBase, 0, 0, smem + 65536, tid);            // B0(0)
  stage_half_B(Bt, KDIM, colBase, 1, 0, smem + 65536 + 16384, tid);    // B1(0)
  stage_half_A(A,  KDIM, rowBase, 1, 0, smem + 16384, tid);            // A1(0)
  stage_half_A(A,  KDIM, rowBase, 0, 64, smem + 32768, tid);           // A0(1)
  stage_half_B(Bt, KDIM, colBase, 0, 64, smem + 65536 + 32768, tid);   // B0(1)
  stage_half_B(Bt, KDIM, colBase, 1, 64, smem + 65536 + 32768 + 16384, tid); // B1(1)
  asm volatile("s_waitcnt vmcnt(4)" ::: "memory");
  __builtin_amdgcn_s_barrier();

  for (int t = 0; t < NT; ++t) {
    char* Ad = smem + (t & 1) * 32768;                 // current dbuf A
    char* Bd = smem + 65536 + (t & 1) * 32768;         // current dbuf B
    char* Ao = smem + ((t + 1) & 1) * 32768;           // other dbuf A

    // ================= phase 1: quadrant (mh=0, nh=0) =================
    {
      const char* aR = Ad + aoff;
      const char* bR = Bd + boff;
#pragma unroll
      for (int m = 0; m < 4; ++m)
#pragma unroll
        for (int ks = 0; ks < 2; ++ks)
          af[m][ks] = *reinterpret_cast<const f16x8*>(aR + m * 2048 + kb[ks]);
#pragma unroll
      for (int n = 0; n < 2; ++n)
#pragma unroll
        for (int ks = 0; ks < 2; ++ks)
          bf0[n][ks] = *reinterpret_cast<const f16x8*>(bR + n * 2048 + kb[ks]);
      if (t + 1 < NT) stage_half_A(A, KDIM, rowBase, 1, (t + 1) * 64, Ao + 16384, tid);
      __builtin_amdgcn_s_barrier();
      asm volatile("s_waitcnt lgkmcnt(0)" ::: "memory");
      __builtin_amdgcn_sched_barrier(0);
      __builtin_amdgcn_s_setprio(1);
#pragma unroll
      for (int ks = 0; ks < 2; ++ks)
#pragma unroll
        for (int m = 0; m < 4; ++m)
#pragma unroll
          for (int n = 0; n < 2; ++n)
            acc[m][n] = __builtin_amdgcn_mfma_f32_16x16x32_f16(af[m][ks], bf0[n][ks], acc[m][n], 0, 0, 0);
      __builtin_amdgcn_s_setprio(0);
      __builtin_amdgcn_s_barrier();
    }

    // ================= phase 2: quadrant (mh=0, nh=1) =================
    {
      const char* bR = Bd + 16384 + boff;
#pragma unroll
      for (int n = 0; n < 2; ++n)
#pragma unroll
        for (int ks = 0; ks < 2; ++ks)
          bf1[n][ks] = *reinterpret_cast<const f16x8*>(bR + n * 2048 + kb[ks]);
      if (t + 2 < NT) stage_half_A(A, KDIM, rowBase, 0, (t + 2) * 64, Ad, tid);
      __builtin_amdgcn_s_barrier();
      asm volatile("s_waitcnt lgkmcnt(0)" ::: "memory");
      __builtin_amdgcn_sched_barrier(0);
      __builtin_amdgcn_s_setprio(1);
#pragma unroll
      for (int ks = 0; ks < 2; ++ks)
#pragma unroll
        for (int m = 0; m < 4; ++m)
#pragma unroll
          for (int n = 0; n < 2; ++n)
            acc[m][2 + n] = __builtin_amdgcn_mfma_f32_16x16x32_f16(af[m][ks], bf1[n][ks], acc[m][2 + n], 0, 0, 0);
      __builtin_amdgcn_s_setprio(0);
      __builtin_amdgcn_s_barrier();
    }

    // ================= phase 3: quadrant (mh=1, nh=1) =================
    {
      const char* aR = Ad + 16384 + aoff;
#pragma unroll
      for (int m = 0; m < 4; ++m)
#pragma unroll
        for (int ks = 0; ks < 2; ++ks)
          af[m][ks] = *reinterpret_cast<const f16x8*>(aR + m * 2048 + kb[ks]);
      if (t + 2 < NT) stage_half_B(Bt, KDIM, colBase, 0, (t + 2) * 64, Bd, tid);
      __builtin_amdgcn_s_barrier();
      asm volatile("s_waitcnt lgkmcnt(0)" ::: "memory");
      __builtin_amdgcn_sched_barrier(0);
      __builtin_amdgcn_s_setprio(1);
#pragma unroll
      for (int ks = 0; ks < 2; ++ks)
#pragma unroll
        for (int m = 0; m < 4; ++m)
#pragma unroll
          for (int n = 0; n < 2; ++n)
            acc[4 + m][2 + n] = __builtin_amdgcn_mfma_f32_16x16x32_f16(af[m][ks], bf1[n][ks], acc[4 + m][2 + n], 0, 0, 0);
      __builtin_amdgcn_s_setprio(0);
      __builtin_amdgcn_s_barrier();
    }

    // ================= phase 4: quadrant (mh=1, nh=0), regs only =======
    {
      if (t + 2 < NT) stage_half_B(Bt, KDIM, colBase, 1, (t + 2) * 64, Bd + 16384, tid);
      // retire tile t+1's 4 half-tiles; keep 3 half-tiles of t+2 in flight
      if (t < NT - 2) { asm volatile("s_waitcnt vmcnt(6)" ::: "memory"); }
      else           { asm volatile("s_waitcnt vmcnt(0)" ::: "memory"); }
      __builtin_amdgcn_s_barrier();
      __builtin_amdgcn_sched_barrier(0);
      __builtin_amdgcn_s_setprio(1);
#pragma unroll
      for (int ks = 0; ks < 2; ++ks)
#pragma unroll
        for (int m = 0; m < 4; ++m)
#pragma unroll
          for (int n = 0; n < 2; ++n)
            acc[4 + m][n] = __builtin_amdgcn_mfma_f32_16x16x32_f16(af[m][ks], bf0[n][ks], acc[4 + m][n], 0, 0, 0);
      __builtin_amdgcn_s_setprio(0);
      __builtin_amdgcn_s_barrier();
    }
  }

  // ---------------- epilogue ----------------
#pragma unroll
  for (int n = 0; n < 4; ++n) {
    const int col = colBase + wc * 64 + n * 16 + lr;
    const float bs = bias[col];
#pragma unroll
    for (int m = 0; m < 8; ++m) {
      const size_t row0 = rowBase + wr * 128 + m * 16 + lg * 4;
#pragma unroll
      for (int i = 0; i < 4; ++i) {
        const size_t idx = (row0 + i) * 4096 + col;
        if (EPI == 0) Pout[idx] = (_Float16)(acc[m][n][i] + bs);
        else          out[idx]  = (acc[m][n][i] + bs) * (float)P[idx];
      }
    }
  }
}

// ---------------------------------------------------------------------------
extern "C" void kernel_launch(void* const* d_in, const int* in_sizes, int n_in,
                              void* d_out, int out_size, void* d_ws, size_t ws_size,
                              hipStream_t stream)
{
  const float* edge_ctx = (const float*)d_in[0];
  const int*   pair_idx = (const int*)d_in[1];
  const float* uf       = (const float*)d_in[2];
  const float* Wpe      = (const float*)d_in[3];
  const float* bpe      = (const float*)d_in[4];
  const float* Wpc      = (const float*)d_in[5];
  const float* bpc      = (const float*)d_in[6];
  const float* Wup      = (const float*)d_in[7];
  const float* bup      = (const float*)d_in[8];
  float* out = (float*)d_out;

  char* ws = (char*)d_ws;
  size_t off = 0;
  _Float16* Pbuf = (_Float16*)(ws + off); off += 536870912;   // 512 MB
  _Float16* Acat = (_Float16*)(ws + off); off += 134217728;   // 128 MB
  _Float16* Auf  = (_Float16*)(ws + off); off += 268435456;   // 256 MB
  _Float16* Btc  = (_Float16*)(ws + off); off += 8388608;     //   8 MB
  _Float16* Btu  = (_Float16*)(ws + off); off += 16777216;    //  16 MB
  _Float16* edge_rep = (_Float16*)(ws + off);                 // 2.6 MB

  (void)hipFuncSetAttribute((const void*)(k_gemm<1024, 0>),
                            hipFuncAttributeMaxDynamicSharedMemorySize, 131072);
  (void)hipFuncSetAttribute((const void*)(k_gemm<2048, 1>),
                            hipFuncAttributeMaxDynamicSharedMemorySize, 131072);

  k_edge<<<160, 256, 0, stream>>>(edge_ctx, Wpe, bpe, edge_rep);
  k_wt<<<(1024 / 64) * (4096 / 64), 256, 0, stream>>>(Wpc, Btc, 1024, 4096);
  k_wt<<<(2048 / 64) * (4096 / 64), 256, 0, stream>>>(Wup, Btu, 2048, 4096);
  k_gather<<<65536, 256, 0, stream>>>(edge_rep, pair_idx, Acat);
  k_cvt<<<65536, 256, 0, stream>>>(uf, Auf);

  k_gemm<1024, 0><<<4096, 512, 131072, stream>>>(Acat, Btc, bpc, nullptr, nullptr, Pbuf);
  k_gemm<2048, 1><<<4096, 512, 131072, stream>>>(Auf, Btu, bup, Pbuf, out, nullptr);
}